// Round 12
// baseline (3116.350 us; speedup 1.0000x reference)
//
#include <hip/hip_runtime.h>
#include <hip/hip_bf16.h>
#include <math.h>

#define S_LEN 256
#define B 32
#define E 512
#define H 512
#define G4 2048          // 4*H
#define T_TAGS 30
#define START_TAG 28
#define STOP_TAG 29

typedef unsigned short u16;
typedef unsigned int   u32;
typedef unsigned long long u64;
typedef __attribute__((ext_vector_type(8))) short bf16x8;
typedef __attribute__((ext_vector_type(4))) float f32x4;

__device__ __forceinline__ float bf2f(u16 u){
  u32 x = ((u32)u) << 16;
  return __uint_as_float(x);
}
__device__ __forceinline__ u16 f2bf(float f){
  u32 x = __float_as_uint(f);
  u32 r = (x + 0x7fffu + ((x >> 16) & 1u)) >> 16;
  return (u16)r;
}
__device__ __forceinline__ float sigf(float x){
  return 1.0f / (1.0f + __expf(-x));
}
__device__ __forceinline__ float tanh_fast(float x){
  return 1.0f - 2.0f / (__expf(2.0f * x) + 1.0f);
}

// ---------------- prep: gather + f32->bf16 for A (emb rows) ----------------
__global__ __launch_bounds__(256) void k_prep_a(
    const int* __restrict__ sent, const float* __restrict__ emb,
    u16* __restrict__ a16)
{
  int g = (blockIdx.x * 256 + threadIdx.x) * 8;      // < 8192*512
  int token = g >> 9, k = g & 511;
  const float* src = emb + (size_t)sent[token] * E + k;
  float4 v0 = *reinterpret_cast<const float4*>(src);
  float4 v1 = *reinterpret_cast<const float4*>(src + 4);
  u16 o[8];
  o[0]=f2bf(v0.x); o[1]=f2bf(v0.y); o[2]=f2bf(v0.z); o[3]=f2bf(v0.w);
  o[4]=f2bf(v1.x); o[5]=f2bf(v1.y); o[6]=f2bf(v1.z); o[7]=f2bf(v1.w);
  *reinterpret_cast<uint4*>(a16 + g) = *reinterpret_cast<const uint4*>(o);
}

// ---------------- prep: generic f32 -> bf16 ----------------
__global__ __launch_bounds__(256) void k_cvt(const float* __restrict__ src, u16* __restrict__ dst){
  int g = (blockIdx.x * 256 + threadIdx.x) * 8;
  float4 v0 = *reinterpret_cast<const float4*>(src + g);
  float4 v1 = *reinterpret_cast<const float4*>(src + g + 4);
  u16 o[8];
  o[0]=f2bf(v0.x); o[1]=f2bf(v0.y); o[2]=f2bf(v0.z); o[3]=f2bf(v0.w);
  o[4]=f2bf(v1.x); o[5]=f2bf(v1.y); o[6]=f2bf(v1.z); o[7]=f2bf(v1.w);
  *reinterpret_cast<uint4*>(dst + g) = *reinterpret_cast<const uint4*>(o);
}

// ---------------- init: h0 -> tagged parity0 (tag 0), parity1 -> tag 0xFFFF ----------------
__global__ __launch_bounds__(256) void k_init_ht(
    const float* __restrict__ h0, u32* __restrict__ ht)
{
  int g = (blockIdx.x * 256 + threadIdx.x) * 8;      // < 2*B*H = 32768
  float4 v0 = *reinterpret_cast<const float4*>(h0 + g);
  float4 v1 = *reinterpret_cast<const float4*>(h0 + g + 4);
  u32 o[8];
  o[0] = ((u32)f2bf(v0.x)) << 16; o[1] = ((u32)f2bf(v0.y)) << 16;
  o[2] = ((u32)f2bf(v0.z)) << 16; o[3] = ((u32)f2bf(v0.w)) << 16;
  o[4] = ((u32)f2bf(v1.x)) << 16; o[5] = ((u32)f2bf(v1.y)) << 16;
  o[6] = ((u32)f2bf(v1.z)) << 16; o[7] = ((u32)f2bf(v1.w)) << 16;
  #pragma unroll
  for (int i = 0; i < 8; ++i){
    ht[g + i] = o[i];                       // parity 0, tag = 0
    ht[32768 + g + i] = 0x0000ffffu;        // parity 1, impossible tag
  }
}

// ---------------- phase A: xw = A16 @ W16^T + bias  (bf16 MFMA, 128x128 tile) ----------------
__global__ __launch_bounds__(256) void k_gemm_xw16(
    const u16* __restrict__ a16, const u16* __restrict__ w16ih,
    const float* __restrict__ b_ih_f, const float* __restrict__ b_hh_f,
    const float* __restrict__ b_ih_b, const float* __restrict__ b_hh_b,
    u16* __restrict__ xw)
{
  int dir = blockIdx.z;
  int n0 = blockIdx.x * 128;
  int m0 = blockIdx.y * 128;
  const u16* Wp = w16ih + (size_t)dir * G4 * E;
  const float* bi = dir ? b_ih_b : b_ih_f;
  const float* bh = dir ? b_hh_b : b_hh_f;
  int tid = threadIdx.x;

  __shared__ u16 As[128 * 32];
  __shared__ u16 Bs[128 * 32];

  int l  = tid & 63;
  int wid = tid >> 6;
  int wr = wid >> 1, wc = wid & 1;
  int lr = l & 15, lh = l >> 4;
  int swzr = (lh ^ (lr & 3)) << 3;

  f32x4 acc[4][4];
  #pragma unroll
  for (int i = 0; i < 4; ++i)
    #pragma unroll
    for (int j = 0; j < 4; ++j)
      acc[i][j] = (f32x4){0.f, 0.f, 0.f, 0.f};

  for (int kt = 0; kt < E; kt += 32){
    __syncthreads();
    #pragma unroll
    for (int it = 0; it < 2; ++it){
      int u = it * 256 + tid;
      int row = u >> 2, c = u & 3;
      int sw = (c ^ (row & 3)) << 3;
      *reinterpret_cast<uint4*>(&As[row * 32 + sw]) =
        *reinterpret_cast<const uint4*>(a16 + (size_t)(m0 + row) * E + kt + c * 8);
      *reinterpret_cast<uint4*>(&Bs[row * 32 + sw]) =
        *reinterpret_cast<const uint4*>(Wp + (size_t)(n0 + row) * E + kt + c * 8);
    }
    __syncthreads();
    bf16x8 a[4], b[4];
    #pragma unroll
    for (int mi = 0; mi < 4; ++mi)
      a[mi] = *reinterpret_cast<const bf16x8*>(&As[(wr * 64 + mi * 16 + lr) * 32 + swzr]);
    #pragma unroll
    for (int ni = 0; ni < 4; ++ni)
      b[ni] = *reinterpret_cast<const bf16x8*>(&Bs[(wc * 64 + ni * 16 + lr) * 32 + swzr]);
    #pragma unroll
    for (int mi = 0; mi < 4; ++mi)
      #pragma unroll
      for (int ni = 0; ni < 4; ++ni)
        acc[mi][ni] = __builtin_amdgcn_mfma_f32_16x16x32_bf16(a[mi], b[ni], acc[mi][ni], 0, 0, 0);
  }

  #pragma unroll
  for (int ni = 0; ni < 4; ++ni){
    int n = n0 + wc * 64 + ni * 16 + lr;
    float bias = bi[n] + bh[n];
    #pragma unroll
    for (int mi = 0; mi < 4; ++mi){
      #pragma unroll
      for (int r = 0; r < 4; ++r){
        int m = m0 + wr * 64 + mi * 16 + lh * 4 + r;
        xw[((size_t)dir * 8192 + m) * G4 + n] = f2bf(acc[mi][ni][r] + bias);
      }
    }
  }
}

// ---------------- persistent bidirectional LSTM: dual-dir interleave + tagged h ----------------
// 32 blocks x 256 threads. Block s owns j-slice [16s,16s+16) for BOTH directions;
// both dirs' W_hh in LDS (128 KB). h words are (bf16<<16)|step_tag, parity
// double-buffered: the sc1 STORE is the publication (no drain, no flags). Dir d's
// tags for step t are written one full other-dir phase before they are read, so
// the speculative first load normally passes -> 1 MALL round trip per phase.
// Retry fallback (validation call / cold start) keeps it correct in all schedules.
__global__ __launch_bounds__(256) void k_lstm_duo(
    const float* __restrict__ w_hh_f, const float* __restrict__ w_hh_b,
    const u16* __restrict__ xw,
    u32* __restrict__ ht,               // [2 parity][2 dir][32][512] tagged u32
    const float* __restrict__ c0,       // [2][32][512] f32
    u16* __restrict__ hseq)             // [2 dir][8192][512] bf16
{
  __shared__ u16   w_s[2][32 * 1024];      // 128 KB (64 rows x 512 per dir)
  __shared__ float gate_s[2][4][32][17];   // [k-half][gate][batch][jj]

  const int slice = blockIdx.x;            // 0..31
  const int j0    = slice << 4;
  const int tid   = threadIdx.x;

  // ---- stage both dirs' w_hh slices (f32 -> bf16) into LDS once ----
  #pragma unroll
  for (int i = 0; i < 32; ++i){
    int u = i * 256 + tid;              // 0..8191 (8-f32 units)
    int d = u >> 12;
    int v = u & 4095;
    int r = v >> 6, ku8 = v & 63;
    int g = r >> 4, jj = r & 15;
    const float* src = (d ? w_hh_b : w_hh_f) + (size_t)((g << 9) + j0 + jj) * H + ku8 * 8;
    float4 a = *reinterpret_cast<const float4*>(src);
    float4 b = *reinterpret_cast<const float4*>(src + 4);
    u16 o[8];
    o[0]=f2bf(a.x); o[1]=f2bf(a.y); o[2]=f2bf(a.z); o[3]=f2bf(a.w);
    o[4]=f2bf(b.x); o[5]=f2bf(b.y); o[6]=f2bf(b.z); o[7]=f2bf(b.w);
    int idx = (r * 512 + ku8 * 8) ^ ((r & 7) << 3);
    *reinterpret_cast<uint4*>(&w_s[d][idx]) = *reinterpret_cast<const uint4*>(o);
  }

  const int l  = tid & 63;
  const int wid = tid >> 6;
  const int wr = wid >> 1;              // batch half
  const int wc = wid & 1;               // k half
  const int lr = l & 15, lh = l >> 4;
  const int sw = (lr & 7) << 3;

  int bbase[4];
  #pragma unroll
  for (int G = 0; G < 4; ++G)
    bbase[G] = (G * 16 + lr) * 512 + (wc << 8) + (lh << 3);

  // consumer tagged-word offset (u64 units): row*256 + wc*128 + lh*4
  const int aoff64 = ((wr << 4) + lr) * 256 + (wc << 7) + (lh << 2);

  // epilogue mapping: thread -> (batch eb, 2 adjacent jj)
  const int eb = tid >> 3;
  const int ej = (tid & 7) << 1;
  float c_reg[2][2];
  #pragma unroll
  for (int d = 0; d < 2; ++d){
    c_reg[d][0] = c0[((size_t)d * B + eb) * H + j0 + ej];
    c_reg[d][1] = c0[((size_t)d * B + eb) * H + j0 + ej + 1];
  }

  const int PSTRIDE64 = B * H;          // u64 units per parity (2*B*H u32 / 2)

  __syncthreads();

  for (int t = 0; t < S_LEN; ++t){
    #pragma unroll
    for (int d = 0; d < 2; ++d){
      const int s_eff = d ? (S_LEN - 1 - t) : t;

      // 1. xw prefetch (independent; hides under the tagged load)
      const u16* xwp = xw + ((size_t)d * 8192 + (size_t)s_eff * B + eb) * G4 + j0 + ej;
      u32 xi = *reinterpret_cast<const u32*>(xwp);
      u32 xf = *reinterpret_cast<const u32*>(xwp + 512);
      u32 xg = *reinterpret_cast<const u32*>(xwp + 1024);
      u32 xo = *reinterpret_cast<const u32*>(xwp + 1536);

      // 2. speculative tagged h read: 32 sc1 u64 loads; retry until all tags == t
      const u64* hp = reinterpret_cast<const u64*>(ht)
                    + (size_t)(t & 1) * PSTRIDE64 + (size_t)d * (PSTRIDE64 >> 1) + aoff64;
      u64 qa[32];
      const u64 ttp = (u64)(u32)t | ((u64)(u32)t << 32);
      for (;;){
        #pragma unroll
        for (int kt = 0; kt < 8; ++kt){
          #pragma unroll
          for (int q = 0; q < 4; ++q)
            qa[kt * 4 + q] = __hip_atomic_load(hp + kt * 16 + q,
                                __ATOMIC_RELAXED, __HIP_MEMORY_SCOPE_AGENT);
        }
        u64 bad = 0;
        #pragma unroll
        for (int i2 = 0; i2 < 32; ++i2) bad |= (qa[i2] ^ ttp);
        if (!__any((bad & 0x0000ffff0000ffffull) != 0)) break;
        __builtin_amdgcn_s_sleep(1);
      }

      // 3. strip tags (v_perm) + MFMA: 4 gate groups x 8 kt over this wave's k-half
      f32x4 acc[4];
      #pragma unroll
      for (int G = 0; G < 4; ++G) acc[G] = (f32x4){0.f, 0.f, 0.f, 0.f};
      #pragma unroll
      for (int kt = 0; kt < 8; ++kt){
        union { u32 w[4]; bf16x8 v; } af;
        #pragma unroll
        for (int q = 0; q < 4; ++q)
          af.w[q] = __builtin_amdgcn_perm((u32)(qa[kt * 4 + q] >> 32),
                                          (u32)(qa[kt * 4 + q]), 0x07060302u);
        #pragma unroll
        for (int G = 0; G < 4; ++G){
          bf16x8 bfr = *reinterpret_cast<const bf16x8*>(&w_s[d][(bbase[G] + (kt << 5)) ^ sw]);
          acc[G] = __builtin_amdgcn_mfma_f32_16x16x32_bf16(af.v, bfr, acc[G], 0, 0, 0);
        }
      }
      #pragma unroll
      for (int G = 0; G < 4; ++G)
        #pragma unroll
        for (int r = 0; r < 4; ++r)
          gate_s[wc][G][(wr << 4) + (lh << 2) + r][lr] = acc[G][r];
      __syncthreads();

      // 4. epilogue: sum k-halves + xw; c/h update; tagged sc1 publish (no drain)
      float hv0, hv1;
      {
        float iv = gate_s[0][0][eb][ej] + gate_s[1][0][eb][ej] + bf2f((u16)(xi & 0xffff));
        float fv = gate_s[0][1][eb][ej] + gate_s[1][1][eb][ej] + bf2f((u16)(xf & 0xffff));
        float gv = gate_s[0][2][eb][ej] + gate_s[1][2][eb][ej] + bf2f((u16)(xg & 0xffff));
        float ov = gate_s[0][3][eb][ej] + gate_s[1][3][eb][ej] + bf2f((u16)(xo & 0xffff));
        float cn = sigf(fv) * c_reg[d][0] + sigf(iv) * tanh_fast(gv);
        hv0 = sigf(ov) * tanh_fast(cn);
        c_reg[d][0] = cn;
      }
      {
        float iv = gate_s[0][0][eb][ej+1] + gate_s[1][0][eb][ej+1] + bf2f((u16)(xi >> 16));
        float fv = gate_s[0][1][eb][ej+1] + gate_s[1][1][eb][ej+1] + bf2f((u16)(xf >> 16));
        float gv = gate_s[0][2][eb][ej+1] + gate_s[1][2][eb][ej+1] + bf2f((u16)(xg >> 16));
        float ov = gate_s[0][3][eb][ej+1] + gate_s[1][3][eb][ej+1] + bf2f((u16)(xo >> 16));
        float cn = sigf(fv) * c_reg[d][1] + sigf(iv) * tanh_fast(gv);
        hv1 = sigf(ov) * tanh_fast(cn);
        c_reg[d][1] = cn;
      }
      u16 h0b = f2bf(hv0), h1b = f2bf(hv1);
      u32 w0 = ((u32)h0b << 16) | (u32)(t + 1);
      u32 w1 = ((u32)h1b << 16) | (u32)(t + 1);
      // tagged u64 store into parity (t+1)&1 — the store IS the publication
      u64* dst = reinterpret_cast<u64*>(ht)
               + (size_t)((t + 1) & 1) * PSTRIDE64 + (size_t)d * (PSTRIDE64 >> 1)
               + ((((size_t)eb << 9) + j0 + ej) >> 1);
      __hip_atomic_store(dst, (u64)w0 | ((u64)w1 << 32),
                         __ATOMIC_RELAXED, __HIP_MEMORY_SCOPE_AGENT);
      // hseq: plain fire-and-forget store (consumed after kernel end)
      *reinterpret_cast<u32*>(hseq + ((size_t)d * 8192 + (size_t)s_eff * B + eb) * H + j0 + ej) =
          (u32)h0b | ((u32)h1b << 16);

      __syncthreads();   // gate_s WAR protection across phases
    }
  }
}

// ---------------- phase C: feats[b][s][t] = [hf;hb] . w_out[t] + b_out[t] ----------------
__global__ __launch_bounds__(256) void k_feats2(
    const u16* __restrict__ hseq, const float* __restrict__ w_out,
    const float* __restrict__ b_out, float* __restrict__ feats)
{
  __shared__ float row[32][1028];
  int blk = blockIdx.x;
  int tid = threadIdx.x;
  const u16* hf16 = hseq;
  const u16* hb16 = hseq + (size_t)8192 * H;

  #pragma unroll
  for (int it = 0; it < 16; ++it){
    int u = it * 256 + tid;
    int flat = u * 8;
    int i = flat >> 10, d = flat & 1023;
    int m = blk * 32 + i;
    const u16* src = (d < 512) ? (hf16 + (size_t)m * H + d) : (hb16 + (size_t)m * H + d - 512);
    uint4 v = *reinterpret_cast<const uint4*>(src);
    float* dst = &row[i][d];
    dst[0] = bf2f((u16)(v.x & 0xffff)); dst[1] = bf2f((u16)(v.x >> 16));
    dst[2] = bf2f((u16)(v.y & 0xffff)); dst[3] = bf2f((u16)(v.y >> 16));
    dst[4] = bf2f((u16)(v.z & 0xffff)); dst[5] = bf2f((u16)(v.z >> 16));
    dst[6] = bf2f((u16)(v.w & 0xffff)); dst[7] = bf2f((u16)(v.w >> 16));
  }
  __syncthreads();

  int i = tid >> 3, tg = tid & 7;
  const float* w0 = w_out + (size_t)((tg + 0  < T_TAGS) ? tg + 0  : 0) * 1024;
  const float* w1 = w_out + (size_t)((tg + 8  < T_TAGS) ? tg + 8  : 0) * 1024;
  const float* w2 = w_out + (size_t)((tg + 16 < T_TAGS) ? tg + 16 : 0) * 1024;
  const float* w3 = w_out + (size_t)((tg + 24 < T_TAGS) ? tg + 24 : 0) * 1024;
  float s0 = 0.f, s1 = 0.f, s2 = 0.f, s3 = 0.f;
  #pragma unroll 4
  for (int k4 = 0; k4 < 256; ++k4){
    float4 rv = *reinterpret_cast<const float4*>(&row[i][k4 * 4]);
    float4 a = *reinterpret_cast<const float4*>(w0 + k4 * 4);
    float4 b = *reinterpret_cast<const float4*>(w1 + k4 * 4);
    float4 c = *reinterpret_cast<const float4*>(w2 + k4 * 4);
    float4 d = *reinterpret_cast<const float4*>(w3 + k4 * 4);
    s0 = fmaf(a.x,rv.x,s0); s0 = fmaf(a.y,rv.y,s0); s0 = fmaf(a.z,rv.z,s0); s0 = fmaf(a.w,rv.w,s0);
    s1 = fmaf(b.x,rv.x,s1); s1 = fmaf(b.y,rv.y,s1); s1 = fmaf(b.z,rv.z,s1); s1 = fmaf(b.w,rv.w,s1);
    s2 = fmaf(c.x,rv.x,s2); s2 = fmaf(c.y,rv.y,s2); s2 = fmaf(c.z,rv.z,s2); s2 = fmaf(c.w,rv.w,s2);
    s3 = fmaf(d.x,rv.x,s3); s3 = fmaf(d.z,rv.z,s3); s3 = fmaf(d.y,rv.y,s3); s3 = fmaf(d.w,rv.w,s3);
  }
  int m = blk * 32 + i;
  int s = m >> 5, bb = m & 31;
  float* fp = feats + ((size_t)bb * S_LEN + s) * T_TAGS;
  float sums[4] = {s0, s1, s2, s3};
  #pragma unroll
  for (int q = 0; q < 4; ++q){
    int tt = tg + q * 8;
    if (tt < T_TAGS) fp[tt] = sums[q] + b_out[tt];
  }
}

// ---------------- phase D: CRF, one wave per batch element, register-resident ----------------
__global__ __launch_bounds__(64) void k_crf2(
    const float* __restrict__ feats, const float* __restrict__ trans,
    const int* __restrict__ tags, float* __restrict__ scores)
{
  int b = blockIdx.x;
  int l = threadIdx.x;

  float trr[T_TAGS];
  #pragma unroll
  for (int j = 0; j < T_TAGS; ++j)
    trr[j] = (l < T_TAGS) ? trans[l * T_TAGS + j] : -1e30f;

  float fv = (l == START_TAG) ? 0.f : -10000.f;
  const float* fb = feats + (size_t)b * S_LEN * T_TAGS;

  for (int s = 0; s < S_LEN; ++s){
    float feat = (l < T_TAGS) ? fb[s * T_TAGS + l] : 0.f;
    float v[T_TAGS];
    float m = -1e30f;
    #pragma unroll
    for (int j = 0; j < T_TAGS; ++j){
      float fvj = __shfl(fv, j);
      v[j] = fvj + trr[j];
      m = fmaxf(m, v[j]);
    }
    float sum = 0.f;
    #pragma unroll
    for (int j = 0; j < T_TAGS; ++j) sum += __expf(v[j] - m);
    fv = feat + m + __logf(sum);
  }

  float fin = (l < T_TAGS) ? fv + trans[STOP_TAG * T_TAGS + l] : -1e30f;
  float mm = fin;
  #pragma unroll
  for (int o = 32; o > 0; o >>= 1) mm = fmaxf(mm, __shfl_xor(mm, o));
  float e = (l < T_TAGS) ? __expf(fin - mm) : 0.f;
  #pragma unroll
  for (int o = 32; o > 0; o >>= 1) e += __shfl_xor(e, o);
  float fsc = mm + __logf(e);

  float g = 0.f;
  #pragma unroll
  for (int it = 0; it < 4; ++it){
    int s = it * 64 + l;
    int nxt = tags[s * B + b];
    int prv = s ? tags[(s - 1) * B + b] : START_TAG;
    g += trans[nxt * T_TAGS + prv] + fb[s * T_TAGS + nxt];
  }
  #pragma unroll
  for (int o = 32; o > 0; o >>= 1) g += __shfl_down(g, o);
  if (l == 0){
    int last = tags[(S_LEN - 1) * B + b];
    g += trans[STOP_TAG * T_TAGS + last];
    scores[b] = fsc - g;
  }
}

__global__ void k_final(const float* __restrict__ scores, float* __restrict__ out){
  int tid = threadIdx.x;
  float v = (tid < B) ? scores[tid] : 0.f;
  #pragma unroll
  for (int o = 32; o > 0; o >>= 1) v += __shfl_down(v, o);
  if (tid == 0) out[0] = v;
}

// ---------------- host ----------------
extern "C" void kernel_launch(void* const* d_in, const int* in_sizes, int n_in,
                              void* d_out, int out_size, void* d_ws, size_t ws_size,
                              hipStream_t stream)
{
  const int*   sent   = (const int*)d_in[0];
  const int*   tags   = (const int*)d_in[1];
  const float* emb    = (const float*)d_in[2];
  const float* w_ih_f = (const float*)d_in[3];
  const float* w_hh_f = (const float*)d_in[4];
  const float* b_ih_f = (const float*)d_in[5];
  const float* b_hh_f = (const float*)d_in[6];
  const float* w_ih_b = (const float*)d_in[7];
  const float* w_hh_b = (const float*)d_in[8];
  const float* b_ih_b = (const float*)d_in[9];
  const float* b_hh_b = (const float*)d_in[10];
  const float* w_out  = (const float*)d_in[11];
  const float* b_out  = (const float*)d_in[12];
  const float* trans  = (const float*)d_in[13];
  const float* h0     = (const float*)d_in[14];
  const float* c0     = (const float*)d_in[15];

  // ws layout (bytes)
  const size_t OFF_XW   = 0;            // bf16 [2][8192][2048] = 64 MiB
  const size_t OFF_A16  = 67108864;     // bf16 [8192][512]     = 8 MiB
  const size_t OFF_WIH  = 75497472;     // bf16 [2][2048][512]  = 4 MiB
  const size_t OFF_HSEQ = 79691776;     // bf16 [2][8192][512]  = 16 MiB
  const size_t OFF_HT   = 96468992;     // u32  [2][2][32][512] = 256 KiB (tagged h)
  const size_t OFF_FEATS= 96731136;     // f32  [32][256][30]   = 960 KiB
  const size_t OFF_SC   = 97714176;     // f32  [32]
  const size_t NEED     = 97714304;
  if (ws_size < NEED) return;

  char* ws = (char*)d_ws;
  u16*   xw     = (u16*)(ws + OFF_XW);
  u16*   a16    = (u16*)(ws + OFF_A16);
  u16*   w16ih  = (u16*)(ws + OFF_WIH);
  u16*   hseq   = (u16*)(ws + OFF_HSEQ);
  u32*   ht     = (u32*)(ws + OFF_HT);
  float* feats  = (float*)(ws + OFF_FEATS);
  float* scores = (float*)(ws + OFF_SC);

  k_prep_a<<<2048, 256, 0, stream>>>(sent, emb, a16);
  k_cvt<<<512, 256, 0, stream>>>(w_ih_f, w16ih);
  k_cvt<<<512, 256, 0, stream>>>(w_ih_b, w16ih + (size_t)G4 * E);
  k_init_ht<<<16, 256, 0, stream>>>(h0, ht);

  k_gemm_xw16<<<dim3(G4 / 128, 8192 / 128, 2), 256, 0, stream>>>(
      a16, w16ih, b_ih_f, b_hh_f, b_ih_b, b_hh_b, xw);

  k_lstm_duo<<<32, 256, 0, stream>>>(w_hh_f, w_hh_b, xw, ht, c0, hseq);

  k_feats2<<<256, 256, 0, stream>>>(hseq, w_out, b_out, feats);
  k_crf2<<<B, 64, 0, stream>>>(feats, trans, tags, scores);
  k_final<<<1, 64, 0, stream>>>(scores, (float*)d_out);
}

// Round 13
// 1603.772 us; speedup vs baseline: 1.9431x; 1.9431x over previous
//
#include <hip/hip_runtime.h>
#include <hip/hip_bf16.h>
#include <math.h>

#define S_LEN 256
#define B 32
#define E 512
#define H 512
#define G4 2048          // 4*H
#define T_TAGS 30
#define START_TAG 28
#define STOP_TAG 29

typedef unsigned short u16;
typedef unsigned int   u32;
typedef unsigned long long u64;
typedef __attribute__((ext_vector_type(8))) short bf16x8;
typedef __attribute__((ext_vector_type(4))) float f32x4;

__device__ __forceinline__ float bf2f(u16 u){
  u32 x = ((u32)u) << 16;
  return __uint_as_float(x);
}
__device__ __forceinline__ u16 f2bf(float f){
  u32 x = __float_as_uint(f);
  u32 r = (x + 0x7fffu + ((x >> 16) & 1u)) >> 16;
  return (u16)r;
}
__device__ __forceinline__ float sigf(float x){
  return 1.0f / (1.0f + __expf(-x));
}
__device__ __forceinline__ float tanh_fast(float x){
  return 1.0f - 2.0f / (__expf(2.0f * x) + 1.0f);
}

// ---------------- prep: gather + f32->bf16 for A (emb rows) ----------------
__global__ __launch_bounds__(256) void k_prep_a(
    const int* __restrict__ sent, const float* __restrict__ emb,
    u16* __restrict__ a16)
{
  int g = (blockIdx.x * 256 + threadIdx.x) * 8;      // < 8192*512
  int token = g >> 9, k = g & 511;
  const float* src = emb + (size_t)sent[token] * E + k;
  float4 v0 = *reinterpret_cast<const float4*>(src);
  float4 v1 = *reinterpret_cast<const float4*>(src + 4);
  u16 o[8];
  o[0]=f2bf(v0.x); o[1]=f2bf(v0.y); o[2]=f2bf(v0.z); o[3]=f2bf(v0.w);
  o[4]=f2bf(v1.x); o[5]=f2bf(v1.y); o[6]=f2bf(v1.z); o[7]=f2bf(v1.w);
  *reinterpret_cast<uint4*>(a16 + g) = *reinterpret_cast<const uint4*>(o);
}

// ---------------- prep: generic f32 -> bf16 ----------------
__global__ __launch_bounds__(256) void k_cvt(const float* __restrict__ src, u16* __restrict__ dst){
  int g = (blockIdx.x * 256 + threadIdx.x) * 8;
  float4 v0 = *reinterpret_cast<const float4*>(src + g);
  float4 v1 = *reinterpret_cast<const float4*>(src + g + 4);
  u16 o[8];
  o[0]=f2bf(v0.x); o[1]=f2bf(v0.y); o[2]=f2bf(v0.z); o[3]=f2bf(v0.w);
  o[4]=f2bf(v1.x); o[5]=f2bf(v1.y); o[6]=f2bf(v1.z); o[7]=f2bf(v1.w);
  *reinterpret_cast<uint4*>(dst + g) = *reinterpret_cast<const uint4*>(o);
}

// ---------------- init: h0 -> bf16 parity0, zero barrier flags ----------------
__global__ __launch_bounds__(256) void k_init16(
    const float* __restrict__ h0, u16* __restrict__ h16, u32* __restrict__ bar)
{
  int g = (blockIdx.x * 256 + threadIdx.x) * 8;      // < 2*B*H = 32768
  float4 v0 = *reinterpret_cast<const float4*>(h0 + g);
  float4 v1 = *reinterpret_cast<const float4*>(h0 + g + 4);
  u16 o[8];
  o[0]=f2bf(v0.x); o[1]=f2bf(v0.y); o[2]=f2bf(v0.z); o[3]=f2bf(v0.w);
  o[4]=f2bf(v1.x); o[5]=f2bf(v1.y); o[6]=f2bf(v1.z); o[7]=f2bf(v1.w);
  *reinterpret_cast<uint4*>(h16 + g) = *reinterpret_cast<const uint4*>(o);
  if (blockIdx.x == 0 && threadIdx.x < 64) bar[threadIdx.x] = 0u;
}

// ---------------- phase A: xw = A16 @ W16^T + bias  (bf16 MFMA, 128x128 tile) ----------------
__global__ __launch_bounds__(256) void k_gemm_xw16(
    const u16* __restrict__ a16, const u16* __restrict__ w16ih,
    const float* __restrict__ b_ih_f, const float* __restrict__ b_hh_f,
    const float* __restrict__ b_ih_b, const float* __restrict__ b_hh_b,
    u16* __restrict__ xw)
{
  int dir = blockIdx.z;
  int n0 = blockIdx.x * 128;
  int m0 = blockIdx.y * 128;
  const u16* Wp = w16ih + (size_t)dir * G4 * E;
  const float* bi = dir ? b_ih_b : b_ih_f;
  const float* bh = dir ? b_hh_b : b_hh_f;
  int tid = threadIdx.x;

  __shared__ u16 As[128 * 32];
  __shared__ u16 Bs[128 * 32];

  int l  = tid & 63;
  int wid = tid >> 6;
  int wr = wid >> 1, wc = wid & 1;
  int lr = l & 15, lh = l >> 4;
  int swzr = (lh ^ (lr & 3)) << 3;

  f32x4 acc[4][4];
  #pragma unroll
  for (int i = 0; i < 4; ++i)
    #pragma unroll
    for (int j = 0; j < 4; ++j)
      acc[i][j] = (f32x4){0.f, 0.f, 0.f, 0.f};

  for (int kt = 0; kt < E; kt += 32){
    __syncthreads();
    #pragma unroll
    for (int it = 0; it < 2; ++it){
      int u = it * 256 + tid;
      int row = u >> 2, c = u & 3;
      int sw = (c ^ (row & 3)) << 3;
      *reinterpret_cast<uint4*>(&As[row * 32 + sw]) =
        *reinterpret_cast<const uint4*>(a16 + (size_t)(m0 + row) * E + kt + c * 8);
      *reinterpret_cast<uint4*>(&Bs[row * 32 + sw]) =
        *reinterpret_cast<const uint4*>(Wp + (size_t)(n0 + row) * E + kt + c * 8);
    }
    __syncthreads();
    bf16x8 a[4], b[4];
    #pragma unroll
    for (int mi = 0; mi < 4; ++mi)
      a[mi] = *reinterpret_cast<const bf16x8*>(&As[(wr * 64 + mi * 16 + lr) * 32 + swzr]);
    #pragma unroll
    for (int ni = 0; ni < 4; ++ni)
      b[ni] = *reinterpret_cast<const bf16x8*>(&Bs[(wc * 64 + ni * 16 + lr) * 32 + swzr]);
    #pragma unroll
    for (int mi = 0; mi < 4; ++mi)
      #pragma unroll
      for (int ni = 0; ni < 4; ++ni)
        acc[mi][ni] = __builtin_amdgcn_mfma_f32_16x16x32_bf16(a[mi], b[ni], acc[mi][ni], 0, 0, 0);
  }

  #pragma unroll
  for (int ni = 0; ni < 4; ++ni){
    int n = n0 + wc * 64 + ni * 16 + lr;
    float bias = bi[n] + bh[n];
    #pragma unroll
    for (int mi = 0; mi < 4; ++mi){
      #pragma unroll
      for (int r = 0; r < 4; ++r){
        int m = m0 + wr * 64 + mi * 16 + lh * 4 + r;
        xw[((size_t)dir * 8192 + m) * G4 + n] = f2bf(acc[mi][ni][r] + bias);
      }
    }
  }
}

// ---------------- persistent bidirectional LSTM: r5 flag protocol, minimized chain ----------------
// 64 blocks x 128 threads (2 waves). dir = bx>>5, slice = bx&31, j0 = slice*16.
// W_hh slice (64 rows x 512) in LDS. Wave wr computes FULL-K gates for batches
// [wr*16, wr*16+16) -> all 4 gates of (batch,j) land in one lane: in-register
// epilogue, NO LDS gate reduce. Sync: r5 flag barrier, but (a) every wave polls
// all 32 flags itself (no poll barrier, no s_sleep), (b) vmcnt(0) drains only
// the 4 sc1 ht stores, (c) hseq HBM stores issue AFTER the flag publish.
__global__ __launch_bounds__(128) void k_lstm_fast(
    const float* __restrict__ w_hh_f, const float* __restrict__ w_hh_b,
    const u16* __restrict__ xw,
    u16* __restrict__ ht,               // [2 parity][2 dir][32][512] bf16
    const float* __restrict__ c0,       // [2][32][512] f32
    u16* __restrict__ hseq,             // [2 dir][8192][512] bf16
    u32* __restrict__ bar)              // [2 dir][32] flags (zeroed each launch)
{
  __shared__ u16 w_s[64 * 512];         // 64 KB, XOR-swizzled

  const int bx    = blockIdx.x;
  const int dir   = bx >> 5;
  const int slice = bx & 31;
  const int j0    = slice << 4;
  const int tid   = threadIdx.x;        // 0..127
  const int l     = tid & 63;
  const int wr    = tid >> 6;           // wave = batch half
  const int lr    = l & 15, lh = l >> 4;
  const int sw    = (lr & 7) << 3;

  // ---- stage w_hh slice (f32 -> bf16) into LDS once ----
  const float* wsrc = dir ? w_hh_b : w_hh_f;
  #pragma unroll
  for (int i = 0; i < 32; ++i){
    int u = i * 128 + tid;              // 0..4095 (8-f32 units)
    int r = u >> 6, ku8 = u & 63;
    int g = r >> 4, jj = r & 15;
    const float* src = wsrc + (size_t)((g << 9) + j0 + jj) * H + ku8 * 8;
    float4 a = *reinterpret_cast<const float4*>(src);
    float4 b = *reinterpret_cast<const float4*>(src + 4);
    u16 o[8];
    o[0]=f2bf(a.x); o[1]=f2bf(a.y); o[2]=f2bf(a.z); o[3]=f2bf(a.w);
    o[4]=f2bf(b.x); o[5]=f2bf(b.y); o[6]=f2bf(b.z); o[7]=f2bf(b.w);
    int idx = (r * 512 + ku8 * 8) ^ ((r & 7) << 3);
    *reinterpret_cast<uint4*>(&w_s[idx]) = *reinterpret_cast<const uint4*>(o);
  }

  int bbase[4];
  #pragma unroll
  for (int G = 0; G < 4; ++G)
    bbase[G] = (G * 16 + lr) * 512 + (lh << 3);

  // A-fragment offset (u16): batch row wr*16+lr, k starts at lh*8
  const int aoff = ((wr << 4) + lr) * 512 + (lh << 3);

  // epilogue: this lane owns (batch = wr*16 + lh*4 + r, j = j0 + lr), r = 0..3
  float c_reg[4];
  #pragma unroll
  for (int r = 0; r < 4; ++r)
    c_reg[r] = c0[((size_t)dir * B + (wr * 16 + lh * 4 + r)) * H + j0 + lr];

  const u32* flg = bar + (dir << 5);
  const int PSTRIDE = 2 * B * H;        // u16 per parity

  __syncthreads();

  for (int t = 0; t < S_LEN; ++t){
    const int s_eff = dir ? (S_LEN - 1 - t) : t;

    // 1. xw prefetch (independent of h; overlaps the poll)
    u16 xv[4][4];
    {
      const u16* xb = xw + ((size_t)dir * 8192 + (size_t)s_eff * B) * G4 + j0 + lr;
      #pragma unroll
      for (int r = 0; r < 4; ++r){
        const u16* xr = xb + (size_t)(wr * 16 + lh * 4 + r) * G4;
        #pragma unroll
        for (int G = 0; G < 4; ++G) xv[G][r] = xr[G << 9];
      }
    }

    // 2. wave-local poll: every wave verifies ALL 32 flags >= t (no block barrier)
    {
      u32 f;
      do {
        f = __hip_atomic_load(flg + (l & 31), __ATOMIC_RELAXED, __HIP_MEMORY_SCOPE_AGENT);
      } while (__any(f < (u32)t));
    }

    // 3. batch-issue 32 coherent (sc1) u64 h loads (full K for this wave's batches)
    const u64* hp = reinterpret_cast<const u64*>(
        ht + (size_t)(t & 1) * PSTRIDE + (size_t)dir * (B * H) + aoff);
    u64 qa[32];
    #pragma unroll
    for (int kt = 0; kt < 16; ++kt){
      qa[2*kt]   = __hip_atomic_load(hp + kt * 8,     __ATOMIC_RELAXED, __HIP_MEMORY_SCOPE_AGENT);
      qa[2*kt+1] = __hip_atomic_load(hp + kt * 8 + 1, __ATOMIC_RELAXED, __HIP_MEMORY_SCOPE_AGENT);
    }

    // 4. MFMA: 4 gates x full K (16 kt) — gates complete in-register
    f32x4 acc[4];
    #pragma unroll
    for (int G = 0; G < 4; ++G) acc[G] = (f32x4){0.f, 0.f, 0.f, 0.f};
    #pragma unroll
    for (int kt = 0; kt < 16; ++kt){
      union { u64 q[2]; bf16x8 v; } ua;
      ua.q[0] = qa[2*kt]; ua.q[1] = qa[2*kt+1];
      #pragma unroll
      for (int G = 0; G < 4; ++G){
        bf16x8 bfr = *reinterpret_cast<const bf16x8*>(&w_s[(bbase[G] + (kt << 5)) ^ sw]);
        acc[G] = __builtin_amdgcn_mfma_f32_16x16x32_bf16(ua.v, bfr, acc[G], 0, 0, 0);
      }
    }

    // 5. in-register epilogue; pair adjacent j via shfl; sc1 publish of h(t+1)
    u32 spack[4];
    #pragma unroll
    for (int r = 0; r < 4; ++r){
      float iv = acc[0][r] + bf2f(xv[0][r]);
      float fv = acc[1][r] + bf2f(xv[1][r]);
      float gv = acc[2][r] + bf2f(xv[2][r]);
      float ov = acc[3][r] + bf2f(xv[3][r]);
      float cn = sigf(fv) * c_reg[r] + sigf(iv) * tanh_fast(gv);
      float hv = sigf(ov) * tanh_fast(cn);
      c_reg[r] = cn;
      u32 hu = (u32)f2bf(hv);
      u32 po = (u32)__shfl_xor((int)hu, 1);
      u32 pack = hu | (po << 16);            // valid on even lr (j, j+1)
      spack[r] = pack;
      if ((lr & 1) == 0){
        int batch = wr * 16 + lh * 4 + r;
        size_t off = ((size_t)dir * B + batch) * H + j0 + lr;   // u16 units, even
        __hip_atomic_store(
            reinterpret_cast<u32*>(ht + (size_t)((t + 1) & 1) * PSTRIDE + off),
            pack, __ATOMIC_RELAXED, __HIP_MEMORY_SCOPE_AGENT);
      }
    }

    // 6. drain ONLY the ht stores, then publish flag
    asm volatile("s_waitcnt vmcnt(0)" ::: "memory");
    __syncthreads();
    if (tid == 0)
      __hip_atomic_store(bar + (dir << 5) + slice, (u32)(t + 1),
                         __ATOMIC_RELAXED, __HIP_MEMORY_SCOPE_AGENT);

    // 7. hseq stores off the critical path (drain under next poll)
    if ((lr & 1) == 0){
      #pragma unroll
      for (int r = 0; r < 4; ++r){
        int batch = wr * 16 + lh * 4 + r;
        *reinterpret_cast<u32*>(
            hseq + ((size_t)dir * 8192 + (size_t)s_eff * B + batch) * H + j0 + lr) = spack[r];
      }
    }
  }
}

// ---------------- phase C: feats[b][s][t] = [hf;hb] . w_out[t] + b_out[t] ----------------
__global__ __launch_bounds__(256) void k_feats2(
    const u16* __restrict__ hseq, const float* __restrict__ w_out,
    const float* __restrict__ b_out, float* __restrict__ feats)
{
  __shared__ float row[32][1028];
  int blk = blockIdx.x;
  int tid = threadIdx.x;
  const u16* hf16 = hseq;
  const u16* hb16 = hseq + (size_t)8192 * H;

  #pragma unroll
  for (int it = 0; it < 16; ++it){
    int u = it * 256 + tid;
    int flat = u * 8;
    int i = flat >> 10, d = flat & 1023;
    int m = blk * 32 + i;
    const u16* src = (d < 512) ? (hf16 + (size_t)m * H + d) : (hb16 + (size_t)m * H + d - 512);
    uint4 v = *reinterpret_cast<const uint4*>(src);
    float* dst = &row[i][d];
    dst[0] = bf2f((u16)(v.x & 0xffff)); dst[1] = bf2f((u16)(v.x >> 16));
    dst[2] = bf2f((u16)(v.y & 0xffff)); dst[3] = bf2f((u16)(v.y >> 16));
    dst[4] = bf2f((u16)(v.z & 0xffff)); dst[5] = bf2f((u16)(v.z >> 16));
    dst[6] = bf2f((u16)(v.w & 0xffff)); dst[7] = bf2f((u16)(v.w >> 16));
  }
  __syncthreads();

  int i = tid >> 3, tg = tid & 7;
  const float* w0 = w_out + (size_t)((tg + 0  < T_TAGS) ? tg + 0  : 0) * 1024;
  const float* w1 = w_out + (size_t)((tg + 8  < T_TAGS) ? tg + 8  : 0) * 1024;
  const float* w2 = w_out + (size_t)((tg + 16 < T_TAGS) ? tg + 16 : 0) * 1024;
  const float* w3 = w_out + (size_t)((tg + 24 < T_TAGS) ? tg + 24 : 0) * 1024;
  float s0 = 0.f, s1 = 0.f, s2 = 0.f, s3 = 0.f;
  #pragma unroll 4
  for (int k4 = 0; k4 < 256; ++k4){
    float4 rv = *reinterpret_cast<const float4*>(&row[i][k4 * 4]);
    float4 a = *reinterpret_cast<const float4*>(w0 + k4 * 4);
    float4 b = *reinterpret_cast<const float4*>(w1 + k4 * 4);
    float4 c = *reinterpret_cast<const float4*>(w2 + k4 * 4);
    float4 d = *reinterpret_cast<const float4*>(w3 + k4 * 4);
    s0 = fmaf(a.x,rv.x,s0); s0 = fmaf(a.y,rv.y,s0); s0 = fmaf(a.z,rv.z,s0); s0 = fmaf(a.w,rv.w,s0);
    s1 = fmaf(b.x,rv.x,s1); s1 = fmaf(b.y,rv.y,s1); s1 = fmaf(b.z,rv.z,s1); s1 = fmaf(b.w,rv.w,s1);
    s2 = fmaf(c.x,rv.x,s2); s2 = fmaf(c.y,rv.y,s2); s2 = fmaf(c.z,rv.z,s2); s2 = fmaf(c.w,rv.w,s2);
    s3 = fmaf(d.x,rv.x,s3); s3 = fmaf(d.y,rv.y,s3); s3 = fmaf(d.z,rv.z,s3); s3 = fmaf(d.w,rv.w,s3);
  }
  int m = blk * 32 + i;
  int s = m >> 5, bb = m & 31;
  float* fp = feats + ((size_t)bb * S_LEN + s) * T_TAGS;
  float sums[4] = {s0, s1, s2, s3};
  #pragma unroll
  for (int q = 0; q < 4; ++q){
    int tt = tg + q * 8;
    if (tt < T_TAGS) fp[tt] = sums[q] + b_out[tt];
  }
}

// ---------------- phase D: CRF, one wave per batch element, register-resident ----------------
__global__ __launch_bounds__(64) void k_crf2(
    const float* __restrict__ feats, const float* __restrict__ trans,
    const int* __restrict__ tags, float* __restrict__ scores)
{
  int b = blockIdx.x;
  int l = threadIdx.x;

  float trr[T_TAGS];
  #pragma unroll
  for (int j = 0; j < T_TAGS; ++j)
    trr[j] = (l < T_TAGS) ? trans[l * T_TAGS + j] : -1e30f;

  float fv = (l == START_TAG) ? 0.f : -10000.f;
  const float* fb = feats + (size_t)b * S_LEN * T_TAGS;

  for (int s = 0; s < S_LEN; ++s){
    float feat = (l < T_TAGS) ? fb[s * T_TAGS + l] : 0.f;
    float v[T_TAGS];
    float m = -1e30f;
    #pragma unroll
    for (int j = 0; j < T_TAGS; ++j){
      float fvj = __shfl(fv, j);
      v[j] = fvj + trr[j];
      m = fmaxf(m, v[j]);
    }
    float sum = 0.f;
    #pragma unroll
    for (int j = 0; j < T_TAGS; ++j) sum += __expf(v[j] - m);
    fv = feat + m + __logf(sum);
  }

  float fin = (l < T_TAGS) ? fv + trans[STOP_TAG * T_TAGS + l] : -1e30f;
  float mm = fin;
  #pragma unroll
  for (int o = 32; o > 0; o >>= 1) mm = fmaxf(mm, __shfl_xor(mm, o));
  float e = (l < T_TAGS) ? __expf(fin - mm) : 0.f;
  #pragma unroll
  for (int o = 32; o > 0; o >>= 1) e += __shfl_xor(e, o);
  float fsc = mm + __logf(e);

  float g = 0.f;
  #pragma unroll
  for (int it = 0; it < 4; ++it){
    int s = it * 64 + l;
    int nxt = tags[s * B + b];
    int prv = s ? tags[(s - 1) * B + b] : START_TAG;
    g += trans[nxt * T_TAGS + prv] + fb[s * T_TAGS + nxt];
  }
  #pragma unroll
  for (int o = 32; o > 0; o >>= 1) g += __shfl_down(g, o);
  if (l == 0){
    int last = tags[(S_LEN - 1) * B + b];
    g += trans[STOP_TAG * T_TAGS + last];
    scores[b] = fsc - g;
  }
}

__global__ void k_final(const float* __restrict__ scores, float* __restrict__ out){
  int tid = threadIdx.x;
  float v = (tid < B) ? scores[tid] : 0.f;
  #pragma unroll
  for (int o = 32; o > 0; o >>= 1) v += __shfl_down(v, o);
  if (tid == 0) out[0] = v;
}

// ---------------- host ----------------
extern "C" void kernel_launch(void* const* d_in, const int* in_sizes, int n_in,
                              void* d_out, int out_size, void* d_ws, size_t ws_size,
                              hipStream_t stream)
{
  const int*   sent   = (const int*)d_in[0];
  const int*   tags   = (const int*)d_in[1];
  const float* emb    = (const float*)d_in[2];
  const float* w_ih_f = (const float*)d_in[3];
  const float* w_hh_f = (const float*)d_in[4];
  const float* b_ih_f = (const float*)d_in[5];
  const float* b_hh_f = (const float*)d_in[6];
  const float* w_ih_b = (const float*)d_in[7];
  const float* w_hh_b = (const float*)d_in[8];
  const float* b_ih_b = (const float*)d_in[9];
  const float* b_hh_b = (const float*)d_in[10];
  const float* w_out  = (const float*)d_in[11];
  const float* b_out  = (const float*)d_in[12];
  const float* trans  = (const float*)d_in[13];
  const float* h0     = (const float*)d_in[14];
  const float* c0     = (const float*)d_in[15];

  // ws layout (bytes)
  const size_t OFF_XW   = 0;            // bf16 [2][8192][2048] = 64 MiB
  const size_t OFF_A16  = 67108864;     // bf16 [8192][512]     = 8 MiB
  const size_t OFF_WIH  = 75497472;     // bf16 [2][2048][512]  = 4 MiB
  const size_t OFF_HSEQ = 79691776;     // bf16 [2][8192][512]  = 16 MiB
  const size_t OFF_HT   = 96468992;     // bf16 [2 parity][2][32][512] = 128 KiB
  const size_t OFF_FEATS= 96600064;     // f32  [32][256][30]   = 960 KiB
  const size_t OFF_SC   = 97583104;     // f32  [32]
  const size_t OFF_BAR  = 97583232;     // u32  [2][32] = 256 B
  const size_t NEED     = 97583488;
  if (ws_size < NEED) return;

  char* ws = (char*)d_ws;
  u16*   xw     = (u16*)(ws + OFF_XW);
  u16*   a16    = (u16*)(ws + OFF_A16);
  u16*   w16ih  = (u16*)(ws + OFF_WIH);
  u16*   hseq   = (u16*)(ws + OFF_HSEQ);
  u16*   ht     = (u16*)(ws + OFF_HT);
  float* feats  = (float*)(ws + OFF_FEATS);
  float* scores = (float*)(ws + OFF_SC);
  u32*   bar    = (u32*)(ws + OFF_BAR);

  k_prep_a<<<2048, 256, 0, stream>>>(sent, emb, a16);
  k_cvt<<<512, 256, 0, stream>>>(w_ih_f, w16ih);
  k_cvt<<<512, 256, 0, stream>>>(w_ih_b, w16ih + (size_t)G4 * E);
  k_init16<<<16, 256, 0, stream>>>(h0, ht, bar);

  k_gemm_xw16<<<dim3(G4 / 128, 8192 / 128, 2), 256, 0, stream>>>(
      a16, w16ih, b_ih_f, b_hh_f, b_ih_b, b_hh_b, xw);

  k_lstm_fast<<<64, 128, 0, stream>>>(w_hh_f, w_hh_b, xw, ht, c0, hseq, bar);

  k_feats2<<<256, 256, 0, stream>>>(hseq, w_out, b_out, feats);
  k_crf2<<<B, 64, 0, stream>>>(feats, trans, tags, scores);
  k_final<<<1, 64, 0, stream>>>(scores, (float*)d_out);
}